// Round 8
// baseline (77.174 us; speedup 1.0000x reference)
//
#include <hip/hip_runtime.h>

#define TGS_D 128
#define TGS_E 20
#define TGS_K 10
#define TGS_F1 276               // 2D+E
#define LDA1 296                 // f16 stride, A1 panel (592B row: banks spread)
#define LDH 136                  // f16 stride, h panel
#define RPB 16                   // rows per block (one M-tile)

typedef _Float16 f16;
typedef _Float16 f16x4 __attribute__((ext_vector_type(4)));
typedef _Float16 f16x8 __attribute__((ext_vector_type(8)));
typedef float    f32x4 __attribute__((ext_vector_type(4)));

// fire-and-forget 16B/lane global->LDS DMA (dest = uniform base + lane*16)
__device__ __forceinline__ void gl_lds16(const void* g, void* l) {
    __builtin_amdgcn_global_load_lds(
        (const __attribute__((address_space(1))) char*)g,
        (__attribute__((address_space(3))) char*)l, 16, 0, 0);
}

// ---------------- NF -> f16 table ----------------
__global__ __launch_bounds__(256)
void tgs_nf16(const float* __restrict__ NF, f16* __restrict__ NF16) {
    const int i = (blockIdx.x * 256 + threadIdx.x) * 8;
    const float4 a = *(const float4*)(NF + i);
    const float4 b = *(const float4*)(NF + i + 4);
    *(f16x8*)(NF16 + i) = f16x8{(f16)a.x, (f16)a.y, (f16)a.z, (f16)a.w,
                                (f16)b.x, (f16)b.y, (f16)b.z, (f16)b.w};
}

// ---------------- merged setup: pack W1, pack W2, tvec ----------------
__global__ __launch_bounds__(128)
void tgs_setup(const float* __restrict__ W1, const float* __restrict__ W2,
               const float* __restrict__ tb, const float* __restrict__ B2,
               f16x8* __restrict__ PW1, f16x8* __restrict__ PW2,
               float* __restrict__ tvec) {
    const int b = blockIdx.x, tid = threadIdx.x;
    if (b < 144) {
        if (tid < 64) {
            const int layer = b / 72, rem = b % 72, ntile = rem / 9, kk = rem % 9;
            const int colg = ntile * 16 + (tid & 15);
            const int kbase = kk * 32 + (tid >> 4) * 8;
            f16x8 v;
            #pragma unroll
            for (int j = 0; j < 8; ++j) {
                const int k = kbase + j;
                v[j] = (k < TGS_F1) ? (f16)W1[(layer * TGS_F1 + k) * TGS_D + colg] : (f16)0.f;
            }
            PW1[b * 64 + tid] = v;
        }
    } else if (b < 272) {
        if (tid < 64) {
            const int bb = b - 144;
            const int layer = bb / 64, rem = bb % 64, ntile = rem / 8, kk = rem % 8;
            const int colg = ntile * 16 + (tid & 15);
            const int kbase = kk * 32 + (tid >> 4) * 8;
            f16x8 v;
            #pragma unroll
            for (int j = 0; j < 8; ++j) {
                const int k = kbase + j;
                const int w2row = (k < TGS_D) ? k : (k + TGS_D);
                v[j] = (f16)W2[(layer * 3 * TGS_D + w2row) * TGS_D + colg];
            }
            PW2[bb * 64 + tid] = v;
        }
    } else {
        const int l = b - 272, d = tid;
        const float* w = W2 + (l * 3 * TGS_D + TGS_D) * TGS_D;
        float acc = B2[l * TGS_D + d];
        for (int j = 0; j < TGS_D; ++j)
            acc = fmaf(__cosf(tb[j]), w[j * TGS_D + d], acc);
        tvec[l * TGS_D + d] = acc;
    }
}

// ---------------- fused per-level kernel ----------------
// 256 threads = 4 waves. Staging via global_load_lds (no VGPR pressure):
//   wave w: 10 issues stage neighbor rows w*4..w*4+3 (16 chunks/row/k),
//           1 issue stages src rows (XOR-swizzled source addresses),
//           up to 4 issues stage EF rows. cos() VALU runs under the DMA.
template<int LEVEL>
__global__ __launch_bounds__(256, 2)
void tgs_agg_kernel(
    const f16* __restrict__ NF16, const float* __restrict__ EF,
    const int* __restrict__ src_ids, const float* __restrict__ ts_arr,
    const int* __restrict__ nbr_idx,   // LEVEL1 only
    const int* __restrict__ eidx, const float* __restrict__ etime,
    const f16* __restrict__ emb_in,    // LEVEL2 only (f16)
    const float* __restrict__ tw, const float* __restrict__ tb,
    const f16x8* __restrict__ PW1, const float* __restrict__ B1,
    const f16x8* __restrict__ PW2, const float* __restrict__ tvec,
    void* __restrict__ out_p)          // LEVEL1: f16 emb; LEVEL2: f32
{
    __shared__ f16   stg[RPB * TGS_K * TGS_D];   // 40,960B raw neighbor rows
    __shared__ float stg_ef[832 * 4];            // 13,312B raw edge rows (+pad)
    __shared__ f16   s_src[RPB * TGS_D];         // 4,096B src panel (swizzled)
    __shared__ f16   snf[RPB][LDA1];             // A1 panel; later aliased as s_out
    __shared__ f16   s_h[RPB][LDH];              // h panel
    __shared__ int   s_nbr[RPB * TGS_K];
    __shared__ int   s_eid[RPB * TGS_K];
    __shared__ float s_et [RPB * TGS_K];
    __shared__ int   s_sid[RPB];
    __shared__ float s_ts [RPB];

    const int tid  = threadIdx.x;
    const int lane = tid & 63;
    const int wid  = tid >> 6;
    const int base_row = blockIdx.x * RPB;

    // ---- stage indices / times ----
    if (tid < RPB * TGS_K) {
        if (LEVEL == 1) s_nbr[tid] = nbr_idx[base_row * TGS_K + tid];
        s_eid[tid] = eidx[base_row * TGS_K + tid];
        s_et [tid] = etime[base_row * TGS_K + tid];
    }
    if (tid < RPB) {
        s_sid[tid] = src_ids[base_row + tid];
        s_ts [tid] = (LEVEL == 1) ? ts_arr[(base_row + tid) / TGS_K] : ts_arr[base_row + tid];
    }
    __syncthreads();

    // ---- phase A: issue ALL gather DMA (fire-and-forget) ----
    // neighbor rows: 2560 chunks of 16B; chunk c -> (er=c>>4, sub=c&15)
    #pragma unroll
    for (int i = 0; i < 10; ++i) {
        const int c  = wid * 640 + i * 64 + lane;
        const int er = c >> 4, sub = c & 15;
        const f16* g = (LEVEL == 1)
            ? NF16 + s_nbr[er] * TGS_D + sub * 8
            : emb_in + base_row * (TGS_K * TGS_D) + c * 8;   // fully sequential
        gl_lds16(g, (char*)stg + (wid * 640 + i * 64) * 16);
    }
    // src rows: 256 chunks; source-side XOR swizzle (phys slot p holds logical p^r)
    {
        const int c = wid * 64 + lane;
        const int r = c >> 4, slot = c & 15;
        const f16* g = NF16 + s_sid[r] * TGS_D + (slot ^ r) * 8;
        gl_lds16(g, (char*)s_src + wid * 1024);
    }
    // edge rows: 800 chunks (+32 pad); chunk c -> (er=c/5, j=c%5)
    #pragma unroll
    for (int i = 0; i < 4; ++i) {
        const int issue = i * 4 + wid;
        if (issue < 13) {
            const int c  = issue * 64 + lane;
            const int ce = (c < 800) ? c : 0;
            const int er = ce / 5, j = ce % 5;
            gl_lds16(EF + s_eid[er] * TGS_E + j * 4, (char*)stg_ef + issue * 1024);
        }
    }

    // ---- phase B (VALU under the DMA): time-encoding K-sum + pad zero ----
    {
        const int sub = tid & 15, r = tid >> 4;
        const float4 w0 = ((const float4*)tw)[sub * 2];
        const float4 w1 = ((const float4*)tw)[sub * 2 + 1];
        const float4 b0 = ((const float4*)tb)[sub * 2];
        const float4 b1 = ((const float4*)tb)[sub * 2 + 1];
        const float ts = s_ts[r];
        float st[8] = {0.f, 0.f, 0.f, 0.f, 0.f, 0.f, 0.f, 0.f};
        #pragma unroll
        for (int k = 0; k < TGS_K; ++k) {
            const float dt = ts - s_et[r * TGS_K + k];
            st[0] += __cosf(fmaf(dt, w0.x, b0.x));
            st[1] += __cosf(fmaf(dt, w0.y, b0.y));
            st[2] += __cosf(fmaf(dt, w0.z, b0.z));
            st[3] += __cosf(fmaf(dt, w0.w, b0.w));
            st[4] += __cosf(fmaf(dt, w1.x, b1.x));
            st[5] += __cosf(fmaf(dt, w1.y, b1.y));
            st[6] += __cosf(fmaf(dt, w1.z, b1.z));
            st[7] += __cosf(fmaf(dt, w1.w, b1.w));
        }
        f16x8 sv;
        #pragma unroll
        for (int j = 0; j < 8; ++j) sv[j] = (f16)st[j];
        *(f16x8*)&snf[r][TGS_D + sub * 8] = sv;
        if (sub >= 5 && sub < 8)   // zero pad [276,288): GEMM1 kk=8 reads it
            *(f16x4*)&snf[r][2 * TGS_D + sub * 4] = f16x4{(f16)0.f, (f16)0.f, (f16)0.f, (f16)0.f};
    }
    __syncthreads();   // drains vmcnt(0): all staged data visible

    // ---- phase C: K-sums from LDS ----
    {
        const int sub = tid & 15, r = tid >> 4;
        float a[8] = {0.f, 0.f, 0.f, 0.f, 0.f, 0.f, 0.f, 0.f};
        #pragma unroll
        for (int k = 0; k < TGS_K; ++k) {
            const f16x8 v = *(const f16x8*)&stg[((r * TGS_K + k) * 16 + sub) * 8];
            #pragma unroll
            for (int j = 0; j < 8; ++j) a[j] += (float)v[j];
        }
        f16x8 av;
        #pragma unroll
        for (int j = 0; j < 8; ++j) av[j] = (f16)a[j];
        *(f16x8*)&snf[r][sub * 8] = av;

        if (sub < 5) {             // edge-feature K-sum (20 f32 = 5 chunks/row)
            float4 e = make_float4(0.f, 0.f, 0.f, 0.f);
            #pragma unroll
            for (int k = 0; k < TGS_K; ++k) {
                const float4 v = *(const float4*)&stg_ef[((r * TGS_K + k) * 5 + sub) * 4];
                e.x += v.x; e.y += v.y; e.z += v.z; e.w += v.w;
            }
            *(f16x4*)&snf[r][2 * TGS_D + sub * 4] = f16x4{(f16)e.x, (f16)e.y, (f16)e.z, (f16)e.w};
        }
    }
    __syncthreads();

    const int ccol = lane & 15;        // C/D col; also A row for frag reads
    const int row0 = (lane >> 4) * 4;  // C/D row base
    const int t0 = 2 * wid, t1 = 2 * wid + 1;

    // ---- GEMM1: h = relu(A1 @ W1 + 10*b1) -> s_h ----
    {
        f16x8 bfa[9], bfb[9];
        #pragma unroll
        for (int kk = 0; kk < 9; ++kk) {
            bfa[kk] = PW1[(t0 * 9 + kk) * 64 + lane];
            bfb[kk] = PW1[(t1 * 9 + kk) * 64 + lane];
        }
        f32x4 acc0 = {0.f, 0.f, 0.f, 0.f}, acc1 = acc0;
        const f16* abase = &snf[ccol][(lane >> 4) * 8];
        #pragma unroll
        for (int kk = 0; kk < 9; ++kk) {
            const f16x8 af = *(const f16x8*)(abase + kk * 32);
            acc0 = __builtin_amdgcn_mfma_f32_16x16x32_f16(af, bfa[kk], acc0, 0, 0, 0);
            acc1 = __builtin_amdgcn_mfma_f32_16x16x32_f16(af, bfb[kk], acc1, 0, 0, 0);
        }
        const float b1v0 = 10.f * B1[t0 * 16 + ccol];
        const float b1v1 = 10.f * B1[t1 * 16 + ccol];
        #pragma unroll
        for (int i = 0; i < 4; ++i) {
            s_h[row0 + i][t0 * 16 + ccol] = (f16)fmaxf(acc0[i] + b1v0, 0.f);
            s_h[row0 + i][t1 * 16 + ccol] = (f16)fmaxf(acc1[i] + b1v1, 0.f);
        }
    }
    __syncthreads();

    // ---- GEMM2: out = [src | h] @ W2cat + tvec ----
    {
        f16x8 bfa[8], bfb[8];
        #pragma unroll
        for (int kk = 0; kk < 8; ++kk) {
            bfa[kk] = PW2[(t0 * 8 + kk) * 64 + lane];
            bfb[kk] = PW2[(t1 * 8 + kk) * 64 + lane];
        }
        f32x4 acc0 = {0.f, 0.f, 0.f, 0.f}, acc1 = acc0;
        #pragma unroll
        for (int kk = 0; kk < 8; ++kk) {
            f16x8 af;
            if (kk < 4) {          // src panel (swizzled LDS read)
                const int q = kk * 4 + (lane >> 4);
                af = *(const f16x8*)&s_src[ccol * 16 * 8 + (q ^ ccol) * 8];
            } else {               // h panel
                af = *(const f16x8*)&s_h[ccol][(kk - 4) * 32 + (lane >> 4) * 8];
            }
            acc0 = __builtin_amdgcn_mfma_f32_16x16x32_f16(af, bfa[kk], acc0, 0, 0, 0);
            acc1 = __builtin_amdgcn_mfma_f32_16x16x32_f16(af, bfb[kk], acc1, 0, 0, 0);
        }
        const float tv0 = tvec[t0 * 16 + ccol];
        const float tv1 = tvec[t1 * 16 + ccol];
        if (LEVEL == 1) {
            // stage f16 to LDS (alias over snf, dead now), then coalesced copy out
            f16* s_out = &snf[0][0];
            #pragma unroll
            for (int i = 0; i < 4; ++i) {
                s_out[(row0 + i) * TGS_D + t0 * 16 + ccol] = (f16)(acc0[i] + tv0);
                s_out[(row0 + i) * TGS_D + t1 * 16 + ccol] = (f16)(acc1[i] + tv1);
            }
            __syncthreads();
            f16* emb_out = (f16*)out_p;
            *(f16x8*)&emb_out[base_row * TGS_D + tid * 8] = *(const f16x8*)&s_out[tid * 8];
        } else {
            float* outf = (float*)out_p;
            #pragma unroll
            for (int i = 0; i < 4; ++i) {
                outf[(base_row + row0 + i) * TGS_D + t0 * 16 + ccol] = acc0[i] + tv0;
                outf[(base_row + row0 + i) * TGS_D + t1 * 16 + ccol] = acc1[i] + tv1;
            }
        }
    }
}

extern "C" void kernel_launch(void* const* d_in, const int* in_sizes, int n_in,
                              void* d_out, int out_size, void* d_ws, size_t ws_size,
                              hipStream_t stream) {
    const float* NF   = (const float*)d_in[0];
    const float* EF   = (const float*)d_in[1];
    const int*   SRC  = (const int*)  d_in[2];
    const float* TS   = (const float*)d_in[3];
    const int*   NBR1 = (const int*)  d_in[4];
    const int*   EI1  = (const int*)  d_in[5];
    const float* ET1  = (const float*)d_in[6];
    const int*   NBR2 = (const int*)  d_in[7];
    const int*   EI2  = (const int*)  d_in[8];
    const float* ET2  = (const float*)d_in[9];
    const float* TW   = (const float*)d_in[10];
    const float* TB   = (const float*)d_in[11];
    const float* W1   = (const float*)d_in[12];  // [2,276,128]
    const float* B1   = (const float*)d_in[13];  // [2,128]
    const float* W2   = (const float*)d_in[14];  // [2,384,128]
    const float* B2   = (const float*)d_in[15];  // [2,128]

    // workspace layout
    f16*   emb16 = (f16*)d_ws;                               // 40960*128*2  = 10,485,760 B
    f16*   NF16  = (f16*)((char*)d_ws + 10485760);           // 100000*128*2 = 25,600,000 B
    char*  wsb   = (char*)d_ws + 10485760 + 25600000;
    f16x8* PW1   = (f16x8*)wsb;                              // 147,456 B
    f16x8* PW2   = (f16x8*)(wsb + 147456);                   // 131,072 B
    float* tvec  = (float*)(wsb + 147456 + 131072);          // 1,024 B

    tgs_nf16 <<<6250, 256, 0, stream>>>(NF, NF16);
    tgs_setup<<<274, 128, 0, stream>>>(W1, W2, TB, B2, PW1, PW2, tvec);

    const int n1 = 4096 * TGS_K;   // 40960 level-1 rows
    const int n2 = 4096;

    // Level 1 (layer-0 weights) -> emb16 (f16)
    tgs_agg_kernel<1><<<n1 / RPB, 256, 0, stream>>>(
        NF16, EF, NBR1, TS, NBR2, EI2, ET2, (const f16*)nullptr,
        TW, TB, PW1, B1, PW2, tvec, emb16);

    // Level 2 (layer-1 weights) -> d_out (f32)
    tgs_agg_kernel<2><<<n2 / RPB, 256, 0, stream>>>(
        NF16, EF, SRC, TS, nullptr, EI1, ET1, emb16,
        TW, TB,
        PW1 + 8 * 9 * 64, B1 + TGS_D,
        PW2 + 8 * 8 * 64, tvec + TGS_D,
        d_out);
}